// Round 6
// baseline (139.021 us; speedup 1.0000x reference)
//
#include <hip/hip_runtime.h>
#include <hip/hip_bf16.h>
#include <stdint.h>

#define N_VOX 65536
#define NK 27

typedef float f32x4 __attribute__((ext_vector_type(4)));
typedef __bf16 bf16x8 __attribute__((ext_vector_type(8)));

#define WAITVM(n) asm volatile("s_waitcnt vmcnt(" #n ")" ::: "memory")

__device__ __forceinline__ void barrier_fence() {
    asm volatile("" ::: "memory");
    __builtin_amdgcn_s_barrier();
    asm volatile("" ::: "memory");
}

// async global->LDS, 16B per lane; LDS dest = M0 + lane*16 (wave-uniform M0)
__device__ __forceinline__ void gll16(const void* src, uint32_t lds_addr) {
    asm volatile("s_mov_b32 m0, %0\n\t"
                 "global_load_lds_dwordx4 %1, off"
                 :: "s"(lds_addr), "v"(src)
                 : "memory");
}

// W[k][c][d] f32 -> Wt pre-swizzled bf16 (inverse-swz source + swz read)
__device__ __forceinline__ void wconv_elem(const float* __restrict__ W,
                                           __bf16* __restrict__ Wt, int Dc, int i) {
    int d = i % Dc;                 // output channel = B row
    int c = (i / Dc) % 64;          // input channel  = B col (K)
    int k = i / (Dc * 64);
    int off = ((d * 128 + ((c >> 3) << 4)) ^ ((d & 7) << 4)) + (c & 7) * 2;
    *(__bf16*)((char*)Wt + (size_t)k * Dc * 128 + off) = (__bf16)W[i];
}

// Fused prep: cvt x (2048) | W1 (432) | W2 (432) | W3 (108) | hist (256) | zp (1)
#define PREP_CVT   2048
#define PREP_W1    432
#define PREP_W2    432
#define PREP_W3    108
#define PREP_HIST  256
#define PREP_GRID  (PREP_CVT + PREP_W1 + PREP_W2 + PREP_W3 + PREP_HIST + 1)
__global__ __launch_bounds__(256) void prep_kernel(
    const float* __restrict__ x, const int* __restrict__ nidx,
    const float* __restrict__ W1, const float* __restrict__ W2, const float* __restrict__ W3,
    __bf16* __restrict__ xb, __bf16* __restrict__ Wt1, __bf16* __restrict__ Wt2,
    __bf16* __restrict__ Wt3, int* __restrict__ pcnt, float* __restrict__ zp)
{
    __shared__ int hcnt[NK];
    const int b = blockIdx.x, tid = threadIdx.x;
    if (b < PREP_CVT) {
        int i = b * 256 + tid;
        const f32x4* xp = (const f32x4*)x;
        f32x4 f0 = xp[i * 2], f1 = xp[i * 2 + 1];
        bf16x8 v;
#pragma unroll
        for (int j = 0; j < 4; ++j) { v[j] = (__bf16)f0[j]; v[4 + j] = (__bf16)f1[j]; }
        ((bf16x8*)xb)[i] = v;
    } else if (b < PREP_CVT + PREP_W1) {
        wconv_elem(W1, Wt1, 64, (b - PREP_CVT) * 256 + tid);
    } else if (b < PREP_CVT + PREP_W1 + PREP_W2) {
        wconv_elem(W2, Wt2, 64, (b - PREP_CVT - PREP_W1) * 256 + tid);
    } else if (b < PREP_CVT + PREP_W1 + PREP_W2 + PREP_W3) {
        wconv_elem(W3, Wt3, 16, (b - PREP_CVT - PREP_W1 - PREP_W2) * 256 + tid);
    } else if (b < PREP_CVT + PREP_W1 + PREP_W2 + PREP_W3 + PREP_HIST) {
        int hb = b - (PREP_CVT + PREP_W1 + PREP_W2 + PREP_W3);
        if (tid < NK) hcnt[tid] = 0;
        __syncthreads();
        const int* np = nidx + ((size_t)hb * 256 + tid) * NK;
#pragma unroll
        for (int k = 0; k < NK; ++k)
            if (np[k] >= 0) atomicAdd(&hcnt[k], 1);
        __syncthreads();
        if (tid < NK) pcnt[hb * NK + tid] = hcnt[tid];
    } else {
        if (tid < 16) ((f32x4*)zp)[tid] = (f32x4){0.f, 0.f, 0.f, 0.f};
    }
}

// 1 block: column-prefix pcnt -> bbase; per-k totals -> tile offsets; mlist padding = -1
#define MAXTILES 2048
__global__ __launch_bounds__(256) void scan_kernel(
    const int* __restrict__ pcnt, int* __restrict__ bbase,
    int* __restrict__ tileoff, int* __restrict__ mlist)
{
    __shared__ int wsum[4];
    __shared__ int P[NK];
    __shared__ int toff[NK + 1];
    const int tid = threadIdx.x, lane = tid & 63, w = tid >> 6;
    int e[NK];
#pragma unroll
    for (int k = 0; k < NK; ++k) {
        int v = pcnt[tid * NK + k];
        int s = v;
#pragma unroll
        for (int d = 1; d < 64; d <<= 1) {
            int t2 = __shfl_up(s, d, 64);
            if (lane >= d) s += t2;
        }
        if (lane == 63) wsum[w] = s;
        __syncthreads();
        int wb = 0;
#pragma unroll
        for (int j = 0; j < 4; ++j) if (j < w) wb += wsum[j];
        e[k] = wb + s - v;                 // exclusive prefix over blocks
        if (tid == 255) P[k] = wb + s;     // total pairs for tap k
        __syncthreads();
    }
    if (tid == 0) {
        int run = 0;
        for (int k = 0; k < NK; ++k) {
            toff[k] = run;
            run += (P[k] + 127) >> 7;
            if (run > MAXTILES) run = MAXTILES;
        }
        toff[NK] = run;
    }
    __syncthreads();
    if (tid < NK + 1) tileoff[tid] = toff[tid];
#pragma unroll
    for (int k = 0; k < NK; ++k)
        bbase[tid * NK + k] = toff[k] * 128 + e[k];
    // padding slots -> -1
    for (int k = 0; k < NK; ++k) {
        int s0 = toff[k] * 128 + P[k];
        int e0 = toff[k + 1] * 128;
        for (int i = s0 + tid; i < e0; i += 256) mlist[i] = -1;
    }
}

// 256 blocks: assign slots, write mlist (k-sorted, tile-aligned) and pos[n][k]
__global__ __launch_bounds__(256) void fill_kernel(
    const int* __restrict__ nidx, const int* __restrict__ bbase,
    int* __restrict__ mlist, int* __restrict__ pos)
{
    __shared__ int lcnt[NK];
    __shared__ int bb[NK];
    const int tid = threadIdx.x;
    if (tid < NK) lcnt[tid] = 0;
    __syncthreads();
    const int n = blockIdx.x * 256 + tid;
    const int* np = nidx + (size_t)n * NK;
    int lr[NK];
#pragma unroll
    for (int k = 0; k < NK; ++k) {
        int m = np[k];
        lr[k] = (m >= 0) ? atomicAdd(&lcnt[k], 1) : -1;
    }
    __syncthreads();
    if (tid < NK) bb[tid] = bbase[blockIdx.x * NK + tid];
    __syncthreads();
    int* pp = pos + (size_t)n * NK;
#pragma unroll
    for (int k = 0; k < NK; ++k) {
        int m = np[k];
        if (m >= 0) {
            int s = bb[k] + lr[k];
            mlist[s] = m;
            pp[k] = s;
        } else pp[k] = -1;
    }
}

// Phase A: per 128-pair tile (tile t -> tap k via tileoff), Y[t*128 + r] = feat[mlist] @ W[k]
template <int NCOLS, bool YF32>
__global__ __launch_bounds__(256, 2) void phaseA(
    const __bf16* __restrict__ feat, const int* __restrict__ mlist,
    const int* __restrict__ tileoff, const __bf16* __restrict__ Wt,
    void* __restrict__ Y, const __bf16* __restrict__ zp)
{
    constexpr int NI = NCOLS / 16;
    constexpr int BSZ = NCOLS * 128;
    __shared__ __align__(16) char lds[16384 + BSZ];
    __shared__ int stoff[NK + 1];
    const int tid = threadIdx.x, lane = tid & 63, wid = tid >> 6;
    const int col = lane & 15, kgrp = lane >> 4;
    if (tid < NK + 1) stoff[tid] = tileoff[tid];
    __syncthreads();
    const int ntiles = stoff[NK];
    const uint32_t ldsbase = (uint32_t)(uintptr_t)(&lds[0]);

    int rA[4], qA[4];
#pragma unroll
    for (int j = 0; j < 4; ++j) {
        int o = (wid * 4 + j) * 1024 + lane * 16;
        rA[j] = o >> 7;
        qA[j] = ((o >> 4) & 7) ^ (rA[j] & 7);
    }

    int k = 0;
    for (int t = blockIdx.x; t < ntiles; t += gridDim.x) {
        while (t >= stoff[k + 1]) ++k;
        const int slot0 = t << 7;
        __syncthreads();                 // LDS reuse across stride iters
        // stage B (weights, pre-swizzled)
        if constexpr (NCOLS == 64) {
#pragma unroll
            for (int j = 0; j < 2; ++j) {
                int jb = wid * 2 + j;
                gll16(Wt + (size_t)k * 4096 + jb * 512 + lane * 8,
                      (uint32_t)__builtin_amdgcn_readfirstlane(
                          (int)(ldsbase + 16384 + jb * 1024)));
            }
        } else {
            if (wid < 2)
                gll16(Wt + (size_t)k * 1024 + wid * 512 + lane * 8,
                      (uint32_t)__builtin_amdgcn_readfirstlane(
                          (int)(ldsbase + 16384 + wid * 1024)));
        }
        // stage A (gathered pairs)
#pragma unroll
        for (int j = 0; j < 4; ++j) {
            int m = mlist[slot0 + rA[j]];
            const __bf16* src = (m >= 0) ? (feat + (size_t)m * 64 + qA[j] * 8) : zp;
            gll16(src, (uint32_t)__builtin_amdgcn_readfirstlane(
                           (int)(ldsbase + (wid * 4 + j) * 1024)));
        }
        WAITVM(0);
        barrier_fence();

        bf16x8 a[2][2];
#pragma unroll
        for (int mi = 0; mi < 2; ++mi) {
            int ar = wid * 32 + mi * 16 + col;
#pragma unroll
            for (int kk = 0; kk < 2; ++kk)
                a[mi][kk] = *(const bf16x8*)(lds + ((ar * 128 + kk * 64 + kgrp * 16)
                                                   ^ ((ar & 7) << 4)));
        }
        f32x4 acc[2][NI];
#pragma unroll
        for (int mi = 0; mi < 2; ++mi)
#pragma unroll
            for (int ni = 0; ni < NI; ++ni)
#pragma unroll
                for (int j = 0; j < 4; ++j) acc[mi][ni][j] = 0.f;
#pragma unroll
        for (int kk = 0; kk < 2; ++kk)
#pragma unroll
            for (int ni = 0; ni < NI; ++ni) {
                int br = ni * 16 + col;
                bf16x8 b = *(const bf16x8*)(lds + 16384 +
                                ((br * 128 + kk * 64 + kgrp * 16) ^ ((br & 7) << 4)));
#pragma unroll
                for (int mi = 0; mi < 2; ++mi)
                    acc[mi][ni] = __builtin_amdgcn_mfma_f32_16x16x32_bf16(
                        a[mi][kk], b, acc[mi][ni], 0, 0, 0);
            }
        // store Y rows (C/D layout: col=lane&15, row=(lane>>4)*4+reg)
#pragma unroll
        for (int mi = 0; mi < 2; ++mi)
#pragma unroll
            for (int ni = 0; ni < NI; ++ni)
#pragma unroll
                for (int reg = 0; reg < 4; ++reg) {
                    size_t row = slot0 + wid * 32 + mi * 16 + kgrp * 4 + reg;
                    int c = ni * 16 + col;
                    if constexpr (YF32)
                        ((float*)Y)[row * 16 + c] = acc[mi][ni][reg];
                    else
                        ((__bf16*)Y)[row * 64 + c] = (__bf16)acc[mi][ni][reg];
                }
    }
}

// Phase B (CH=64): out[n] = relu(bias + sum_k Y[pos[n][k]])
template <bool RELU>
__global__ __launch_bounds__(256) void phaseB64(
    const int* __restrict__ pos, const __bf16* __restrict__ Y,
    const float* __restrict__ bias, __bf16* __restrict__ dst)
{
    const int gid = blockIdx.x * 256 + threadIdx.x;
    const int n = gid >> 2, q = gid & 3;
    const int* pn = pos + (size_t)n * NK;
    float acc[16];
#pragma unroll
    for (int i = 0; i < 16; ++i) acc[i] = bias[q * 16 + i];
#pragma unroll
    for (int k = 0; k < NK; ++k) {
        int p = pn[k];
        if (p >= 0) {
            const bf16x8* yr = (const bf16x8*)(Y + (size_t)p * 64 + q * 16);
            bf16x8 y0 = yr[0], y1 = yr[1];
#pragma unroll
            for (int i = 0; i < 8; ++i) {
                acc[i] += (float)y0[i];
                acc[8 + i] += (float)y1[i];
            }
        }
    }
    bf16x8 o0, o1;
#pragma unroll
    for (int i = 0; i < 8; ++i) {
        float v0 = acc[i], v1 = acc[8 + i];
        if (RELU) { v0 = fmaxf(v0, 0.f); v1 = fmaxf(v1, 0.f); }
        o0[i] = (__bf16)v0;
        o1[i] = (__bf16)v1;
    }
    bf16x8* dp = (bf16x8*)(dst + (size_t)n * 64 + q * 16);
    dp[0] = o0;
    dp[1] = o1;
}

// Phase B (COUT=16, f32): out[n] = bias + sum_k Y3[pos[n][k]]
__global__ __launch_bounds__(256) void phaseB16(
    const int* __restrict__ pos, const float* __restrict__ Y,
    const float* __restrict__ bias, float* __restrict__ out)
{
    const int n = blockIdx.x * 256 + threadIdx.x;
    const int* pn = pos + (size_t)n * NK;
    float acc[16];
#pragma unroll
    for (int i = 0; i < 16; ++i) acc[i] = bias[i];
#pragma unroll
    for (int k = 0; k < NK; ++k) {
        int p = pn[k];
        if (p >= 0) {
            const f32x4* yr = (const f32x4*)(Y + (size_t)p * 16);
#pragma unroll
            for (int j = 0; j < 4; ++j) {
                f32x4 v = yr[j];
#pragma unroll
                for (int i = 0; i < 4; ++i) acc[j * 4 + i] += v[i];
            }
        }
    }
    f32x4* op = (f32x4*)(out + (size_t)n * 16);
#pragma unroll
    for (int j = 0; j < 4; ++j) {
        f32x4 v;
#pragma unroll
        for (int i = 0; i < 4; ++i) v[i] = acc[j * 4 + i];
        op[j] = v;
    }
}

extern "C" void kernel_launch(void* const* d_in, const int* in_sizes, int n_in,
                              void* d_out, int out_size, void* d_ws, size_t ws_size,
                              hipStream_t stream) {
    const float* x  = (const float*)d_in[0];
    const int* nidx = (const int*)d_in[1];
    const float* W1 = (const float*)d_in[2];
    const float* b1 = (const float*)d_in[3];
    const float* W2 = (const float*)d_in[4];
    const float* b2 = (const float*)d_in[5];
    const float* W3 = (const float*)d_in[6];
    const float* b3 = (const float*)d_in[7];

    char* ws = (char*)d_ws;
    __bf16* buf0 = (__bf16*)ws;                         // xb, later h2 (8 MB)
    __bf16* buf1 = (__bf16*)(ws + (8u << 20));          // h1 (8 MB)
    __bf16* Wt1  = (__bf16*)(ws + (16u << 20));
    __bf16* Wt2  = (__bf16*)(ws + (16u << 20) + 262144);
    __bf16* Wt3  = (__bf16*)(ws + (16u << 20) + 524288);
    __bf16* zp   = (__bf16*)(ws + (16u << 20) + 786432);   // 256B zeros
    int* pcnt    = (int*)(ws + (16u << 20) + 851968);      // [256][27]
    int* bbase   = (int*)(ws + (16u << 20) + 917504);      // [256][27]
    int* tileoff = (int*)(ws + (16u << 20) + 983040);      // [28]
    int* pos     = (int*)(ws + (17u << 20));               // [N][27]  ~6.75 MB
    int* mlist   = (int*)(ws + (24u << 20));               // [MAXTILES*128]  1 MB
    void* Ybuf   = (void*)(ws + (25u << 20));              // 32 MB

    prep_kernel<<<PREP_GRID, 256, 0, stream>>>(x, nidx, W1, W2, W3,
                                               buf0, Wt1, Wt2, Wt3, pcnt, (float*)zp);
    scan_kernel<<<1, 256, 0, stream>>>(pcnt, bbase, tileoff, mlist);
    fill_kernel<<<256, 256, 0, stream>>>(nidx, bbase, mlist, pos);

    // layer 1
    phaseA<64, false><<<2048, 256, 0, stream>>>(buf0, mlist, tileoff, Wt1, Ybuf, zp);
    phaseB64<true><<<N_VOX * 4 / 256, 256, 0, stream>>>(pos, (const __bf16*)Ybuf, b1, buf1);
    // layer 2
    phaseA<64, false><<<2048, 256, 0, stream>>>(buf1, mlist, tileoff, Wt2, Ybuf, zp);
    phaseB64<true><<<N_VOX * 4 / 256, 256, 0, stream>>>(pos, (const __bf16*)Ybuf, b2, buf0);
    // layer 3
    phaseA<16, true><<<2048, 256, 0, stream>>>(buf0, mlist, tileoff, Wt3, Ybuf, zp);
    phaseB16<<<N_VOX / 256, 256, 0, stream>>>(pos, (const float*)Ybuf, b3, (float*)d_out);
}

// Round 7
// 80.535 us; speedup vs baseline: 1.7262x; 1.7262x over previous
//
#include <hip/hip_runtime.h>
#include <hip/hip_bf16.h>
#include <stdint.h>

#define N_VOX 65536
#define NK 27
#define BR 64          // rows per block

typedef float f32x4 __attribute__((ext_vector_type(4)));
typedef __bf16 bf16x8 __attribute__((ext_vector_type(8)));

#define WAITVM(n) asm volatile("s_waitcnt vmcnt(" #n ")" ::: "memory")

__device__ __forceinline__ void barrier_fence() {
    asm volatile("" ::: "memory");
    __builtin_amdgcn_s_barrier();
    asm volatile("" ::: "memory");
}

// async global->LDS, 16B per lane; LDS dest = M0 + lane*16 (wave-uniform M0)
__device__ __forceinline__ void gll16(const void* src, uint32_t lds_addr) {
    asm volatile("s_mov_b32 m0, %0\n\t"
                 "global_load_lds_dwordx4 %1, off"
                 :: "s"(lds_addr), "v"(src)
                 : "memory");
}

// W[k][c][d] f32 -> Wt pre-swizzled bf16 so a LINEAR 1KB-per-wave global_load_lds
// produces the XOR-swizzled LDS image directly (inverse-swz source + swz read).
__device__ __forceinline__ void wconv_elem(const float* __restrict__ W,
                                           __bf16* __restrict__ Wt, int Dc, int i) {
    int d = i % Dc;                 // output channel = B row
    int c = (i / Dc) % 64;          // input channel  = B col (K)
    int k = i / (Dc * 64);
    int off = ((d * 128 + ((c >> 3) << 4)) ^ ((d & 7) << 4)) + (c & 7) * 2;
    *(__bf16*)((char*)Wt + (size_t)k * Dc * 128 + off) = (__bf16)W[i];
}

// Fused prep: x f32->bf16 (2048 blocks) | W1 (432) | W2 (432) | W3 (108)
#define PREP_CVT   2048
#define PREP_W1    432
#define PREP_W2    432
#define PREP_W3    108
#define PREP_GRID  (PREP_CVT + PREP_W1 + PREP_W2 + PREP_W3)
__global__ __launch_bounds__(256) void prep_kernel(
    const float* __restrict__ x,
    const float* __restrict__ W1, const float* __restrict__ W2, const float* __restrict__ W3,
    __bf16* __restrict__ xb, __bf16* __restrict__ Wt1, __bf16* __restrict__ Wt2,
    __bf16* __restrict__ Wt3)
{
    const int b = blockIdx.x, tid = threadIdx.x;
    if (b < PREP_CVT) {
        int i = b * 256 + tid;                      // 8 elems/thread, covers N*64
        const f32x4* xp = (const f32x4*)x;
        f32x4 f0 = xp[i * 2], f1 = xp[i * 2 + 1];
        bf16x8 v;
#pragma unroll
        for (int j = 0; j < 4; ++j) { v[j] = (__bf16)f0[j]; v[4 + j] = (__bf16)f1[j]; }
        ((bf16x8*)xb)[i] = v;
    } else if (b < PREP_CVT + PREP_W1) {
        wconv_elem(W1, Wt1, 64, (b - PREP_CVT) * 256 + tid);
    } else if (b < PREP_CVT + PREP_W1 + PREP_W2) {
        wconv_elem(W2, Wt2, 64, (b - PREP_CVT - PREP_W1) * 256 + tid);
    } else {
        wconv_elem(W3, Wt3, 16, (b - PREP_CVT - PREP_W1 - PREP_W2) * 256 + tid);
    }
}

// One layer: out[n,:] = bias + sum_k feat[nbr(n,k)] @ W[k]   (invalid nbr -> 0)
// WR x WC wave grid. Valid neighbor rows are COMPACTED per (block,k) into a
// small LDS region (u16 cm list + u8 slot map built via __ballot scan);
// invalid rows read a shared 128B LDS zero row (same-address broadcast = free).
// B (weights) double-buffered via global_load_lds; counted-vmcnt pipeline.
template <int NCOLS, bool RELU, bool OUT_F32>
__global__ __launch_bounds__(256, 4) void conv_layer(
    const __bf16* __restrict__ feat,      // [N,64] bf16
    const int* __restrict__ nidx,         // [N,27]
    const __bf16* __restrict__ Wt,        // [27][NCOLS*64] pre-swizzled bf16
    const float* __restrict__ bias,       // [NCOLS]
    void* __restrict__ dst)               // [N,NCOLS]
{
    constexpr int WC = (NCOLS == 64) ? 2 : 1;   // col-split waves
    constexpr int WR = 4 / WC;                  // row-split waves
    constexpr int MI = BR / (WR * 16);          // 2 (CH) or 1 (COUT)
    constexpr int NI = NCOLS / (WC * 16);       // 2 (CH) or 1 (COUT)
    constexpr int ABUF = BR * 128;              // 8K compact-A buffer (worst case all valid)
    constexpr int BSZ = NCOLS * 128;            // B tile bytes
    constexpr int BBASE = 2 * ABUF;             // 16384
    constexpr int CMOFF = BBASE + 2 * BSZ;
    constexpr int SLOTOFF = CMOFF + NK * 64 * 2;      // u16 cm [27][64]
    constexpr int CNTOFF = SLOTOFF + NK * 64;         // u8 slotmap [27][64]
    constexpr int ZROFF = CNTOFF + ((NK * 4 + 15) & ~15);
    __shared__ __align__(16) char lds[ZROFF + 128];

    const int tid = threadIdx.x;
    const int lane = tid & 63;
    const int wid = tid >> 6;
    const int wr = wid / WC;
    const int wc = wid % WC;
    const int col = lane & 15;
    const int kgrp = lane >> 4;
    const int row0 = blockIdx.x * BR;

    uint16_t* cm = (uint16_t*)(lds + CMOFF);
    uint8_t* smap = (uint8_t*)(lds + SLOTOFF);
    int* cnt = (int*)(lds + CNTOFF);

    // ---- preload nidx slab into (temporary) A region, transposed ----
    int* snid = (int*)lds;                       // 6912 B <= ABUF*2
    const int* gnid = nidx + (size_t)row0 * NK;
    for (int i = tid; i < BR * NK; i += 256) {
        int r = i / NK;
        int kk = i - r * NK;
        snid[kk * BR + r] = gnid[i];
    }
    __syncthreads();
    // ---- build compact lists: wave w handles taps k = w, w+4, ... ----
#pragma unroll
    for (int j = 0; j < 7; ++j) {
        int k = wid + 4 * j;
        if (k < NK) {
            int m = snid[k * BR + lane];
            unsigned long long bm = __ballot(m >= 0);
            int slot = __popcll(bm & ((1ull << lane) - 1ull));
            if (m >= 0) cm[k * 64 + slot] = (uint16_t)m;
            smap[k * 64 + lane] = (m >= 0) ? (uint8_t)slot : (uint8_t)255;
            if (lane == 0) cnt[k] = (int)__popcll(bm);
        }
    }
    if (tid < 8) *(f32x4*)(lds + ZROFF + tid * 16) = (f32x4){0.f, 0.f, 0.f, 0.f};
    __syncthreads();

    const uint32_t ldsbase = (uint32_t)(uintptr_t)(&lds[0]);
    const char* featB = (const char*)feat;
    const int nBn = (NCOLS == 64) ? 2 : ((wid < 2) ? 1 : 0);

    auto issueB = [&](int k, int buf) {
        if constexpr (NCOLS == 64) {
#pragma unroll
            for (int j = 0; j < 2; ++j) {
                int jb = wid * 2 + j;
                gll16(Wt + (size_t)k * 4096 + jb * 512 + lane * 8,
                      (uint32_t)__builtin_amdgcn_readfirstlane(
                          (int)(ldsbase + BBASE + buf * BSZ + jb * 1024)));
            }
        } else {
            if (wid < 2)
                gll16(Wt + (size_t)k * 1024 + wid * 512 + lane * 8,
                      (uint32_t)__builtin_amdgcn_readfirstlane(
                          (int)(ldsbase + BBASE + buf * BSZ + wid * 1024)));
        }
    };

    // stage only the v valid rows (compacted); O = ceil(v/8) 1KB wave-ops
    auto issueA = [&](int k, int buf, int v, int O) {
#pragma unroll
        for (int t = 0; t < 2; ++t) {
            int i = wid + 4 * t;
            if (i < O) {
                int g = i * 64 + lane;
                int s = g >> 3, q = g & 7;
                int m = cm[k * 64 + s];
                const char* src = featB + (size_t)m * 128 + ((q ^ (s & 7)) << 4);
                uint32_t la = (uint32_t)__builtin_amdgcn_readfirstlane(
                                  (int)(ldsbase + buf * ABUF + i * 1024));
                if (g < v * 8) gll16(src, la);
            }
        }
    };

    f32x4 acc[MI][NI];
#pragma unroll
    for (int mi = 0; mi < MI; ++mi)
#pragma unroll
        for (int ni = 0; ni < NI; ++ni)
#pragma unroll
            for (int j = 0; j < 4; ++j) acc[mi][ni][j] = 0.f;

    auto compute = [&](int k, int buf) {
        bf16x8 a[MI][2], b[NI][2];
#pragma unroll
        for (int mi = 0; mi < MI; ++mi) {
            int ar = wr * (MI * 16) + mi * 16 + col;
            int s8 = (int)smap[k * 64 + ar];
#pragma unroll
            for (int kk = 0; kk < 2; ++kk) {
                int kb = kk * 64 + kgrp * 16;
                int aoff = (s8 == 255) ? (ZROFF + kb)
                         : (buf * ABUF + ((s8 * 128 + kb) ^ ((s8 & 7) << 4)));
                a[mi][kk] = *(const bf16x8*)(lds + aoff);
            }
        }
#pragma unroll
        for (int ni = 0; ni < NI; ++ni) {
            int br = wc * (NI * 16) + ni * 16 + col;
#pragma unroll
            for (int kk = 0; kk < 2; ++kk)
                b[ni][kk] = *(const bf16x8*)(lds + BBASE + buf * BSZ +
                                ((br * 128 + kk * 64 + kgrp * 16) ^ ((br & 7) << 4)));
        }
#pragma unroll
        for (int kk = 0; kk < 2; ++kk)
#pragma unroll
            for (int mi = 0; mi < MI; ++mi)
#pragma unroll
                for (int ni = 0; ni < NI; ++ni)
                    acc[mi][ni] = __builtin_amdgcn_mfma_f32_16x16x32_bf16(
                        a[mi][kk], b[ni][kk], acc[mi][ni], 0, 0, 0);
    };

    issueB(0, 0);
    { int v0 = cnt[0]; issueA(0, 0, v0, (v0 + 7) >> 3); }

    for (int k = 0; k < NK; ++k) {
        const int buf = k & 1;
        barrier_fence();                    // readers of buf^1 are done
        if (k + 1 < NK) {
            issueB(k + 1, buf ^ 1);
            int vN = cnt[k + 1];
            int ON = (vN + 7) >> 3;
            issueA(k + 1, buf ^ 1, vN, ON);
            // retire all own k-ops; own (k+1)-ops stay in flight.
            int T = nBn + (ON > wid) + (ON > wid + 4);
            switch (T) {
                case 0: WAITVM(0); break;
                case 1: WAITVM(1); break;
                case 2: WAITVM(2); break;
                case 3: WAITVM(3); break;
                default: WAITVM(4); break;
            }
        } else {
            WAITVM(0);
        }
        barrier_fence();                    // all waves' k-tiles landed
        compute(k, buf);
    }

    // ---- epilogue: C/D layout col=lane&15, row=(lane>>4)*4+reg ----
#pragma unroll
    for (int ni = 0; ni < NI; ++ni) {
        int c = wc * (NI * 16) + ni * 16 + col;
        float bv = bias[c];
#pragma unroll
        for (int mi = 0; mi < MI; ++mi) {
#pragma unroll
            for (int reg = 0; reg < 4; ++reg) {
                int r = row0 + wr * (MI * 16) + mi * 16 + kgrp * 4 + reg;
                float v = acc[mi][ni][reg] + bv;
                if (RELU) v = fmaxf(v, 0.f);
                if (OUT_F32) ((float*)dst)[(size_t)r * NCOLS + c] = v;
                else ((__bf16*)dst)[(size_t)r * NCOLS + c] = (__bf16)v;
            }
        }
    }
}

extern "C" void kernel_launch(void* const* d_in, const int* in_sizes, int n_in,
                              void* d_out, int out_size, void* d_ws, size_t ws_size,
                              hipStream_t stream) {
    const float* x  = (const float*)d_in[0];
    const int* nidx = (const int*)d_in[1];
    const float* W1 = (const float*)d_in[2];
    const float* b1 = (const float*)d_in[3];
    const float* W2 = (const float*)d_in[4];
    const float* b2 = (const float*)d_in[5];
    const float* W3 = (const float*)d_in[6];
    const float* b3 = (const float*)d_in[7];

    // ws: buf0(8MB: xb, later h2) | buf1(8MB: h1) | Wt1 | Wt2 | Wt3
    char* ws = (char*)d_ws;
    __bf16* buf0 = (__bf16*)ws;
    __bf16* buf1 = (__bf16*)(ws + 8388608);
    __bf16* Wt1  = (__bf16*)(ws + 16777216);
    __bf16* Wt2  = Wt1 + 27 * 64 * 64;
    __bf16* Wt3  = Wt2 + 27 * 64 * 64;

    prep_kernel<<<PREP_GRID, 256, 0, stream>>>(x, W1, W2, W3, buf0, Wt1, Wt2, Wt3);

    dim3 grid(N_VOX / BR);
    conv_layer<64, true,  false><<<grid, 256, 0, stream>>>(buf0, nidx, Wt1, b1, buf1);
    conv_layer<64, true,  false><<<grid, 256, 0, stream>>>(buf1, nidx, Wt2, b2, buf0);
    conv_layer<16, false, true ><<<grid, 256, 0, stream>>>(buf0, nidx, Wt3, b3, d_out);
}

// Round 9
// 69.111 us; speedup vs baseline: 2.0116x; 1.1653x over previous
//
#include <hip/hip_runtime.h>
#include <hip/hip_bf16.h>
#include <stdint.h>

#define N_VOX 65536
#define NK 27
#define BR 64          // rows per block

typedef float f32x4 __attribute__((ext_vector_type(4)));
typedef int   i32x2 __attribute__((ext_vector_type(2)));
typedef __bf16 bf16x8 __attribute__((ext_vector_type(8)));

#define WAITVM(n) asm volatile("s_waitcnt vmcnt(" #n ")" ::: "memory")

__device__ __forceinline__ void barrier_fence() {
    asm volatile("" ::: "memory");
    __builtin_amdgcn_s_barrier();
    asm volatile("" ::: "memory");
}

// async global->LDS, 16B per lane; LDS dest = M0 + lane*16 (wave-uniform M0)
__device__ __forceinline__ void gll16(const void* src, uint32_t lds_addr) {
    asm volatile("s_mov_b32 m0, %0\n\t"
                 "global_load_lds_dwordx4 %1, off"
                 :: "s"(lds_addr), "v"(src)
                 : "memory");
}

// W[k][c][d] f32 -> Wt pre-swizzled bf16 so a LINEAR 1KB-per-wave global_load_lds
// produces the XOR-swizzled LDS image directly (inverse-swz source + swz read).
__device__ __forceinline__ void wconv_elem(const float* __restrict__ W,
                                           __bf16* __restrict__ Wt, int Dc, int i) {
    int d = i % Dc;                 // output channel = B row
    int c = (i / Dc) % 64;          // input channel  = B col (K)
    int k = i / (Dc * 64);
    int off = ((d * 128 + ((c >> 3) << 4)) ^ ((d & 7) << 4)) + (c & 7) * 2;
    *(__bf16*)((char*)Wt + (size_t)k * Dc * 128 + off) = (__bf16)W[i];
}

// Fused prep: x f32->bf16 (2048) | W1 (432) | W2 (432) | W3 (108) | zero page (1)
#define PREP_CVT   2048
#define PREP_W1    432
#define PREP_W2    432
#define PREP_W3    108
#define PREP_GRID  (PREP_CVT + PREP_W1 + PREP_W2 + PREP_W3 + 1)
__global__ __launch_bounds__(256) void prep_kernel(
    const float* __restrict__ x,
    const float* __restrict__ W1, const float* __restrict__ W2, const float* __restrict__ W3,
    __bf16* __restrict__ xb, __bf16* __restrict__ Wt1, __bf16* __restrict__ Wt2,
    __bf16* __restrict__ Wt3, float* __restrict__ zp)
{
    const int b = blockIdx.x, tid = threadIdx.x;
    if (b < PREP_CVT) {
        int i = b * 256 + tid;                      // 8 elems/thread, covers N*64
        const f32x4* xp = (const f32x4*)x;
        f32x4 f0 = xp[i * 2], f1 = xp[i * 2 + 1];
        bf16x8 v;
#pragma unroll
        for (int j = 0; j < 4; ++j) { v[j] = (__bf16)f0[j]; v[4 + j] = (__bf16)f1[j]; }
        ((bf16x8*)xb)[i] = v;
    } else if (b < PREP_CVT + PREP_W1) {
        wconv_elem(W1, Wt1, 64, (b - PREP_CVT) * 256 + tid);
    } else if (b < PREP_CVT + PREP_W1 + PREP_W2) {
        wconv_elem(W2, Wt2, 64, (b - PREP_CVT - PREP_W1) * 256 + tid);
    } else if (b < PREP_CVT + PREP_W1 + PREP_W2 + PREP_W3) {
        wconv_elem(W3, Wt3, 16, (b - PREP_CVT - PREP_W1 - PREP_W2) * 256 + tid);
    } else {
        if (tid < 16) ((f32x4*)zp)[tid] = (f32x4){0.f, 0.f, 0.f, 0.f};  // 256B zero page
    }
}

// One layer: out[n,:] = bias + sum_k feat[nbr(n,k)] @ W[k]   (invalid nbr -> 0)
// R3-proven pipeline (double-buffered gll16 staging, counted vmcnt, 2 barriers/k).
// vs R3: 2x2 wave grid for CH (B-read dup 4x->2x), permuted snid slab so each
// wave's 2 gather-row indices come from ONE ds_read_b64, lane-constant inv-swz.
template <int NCOLS, bool RELU, bool OUT_F32>
__global__ __launch_bounds__(256, 4) void conv_layer(
    const __bf16* __restrict__ feat,      // [N,64] bf16
    const int* __restrict__ nidx,         // [N,27]
    const __bf16* __restrict__ Wt,        // [27][NCOLS*64] pre-swizzled bf16
    const float* __restrict__ bias,       // [NCOLS]
    void* __restrict__ dst,               // [N,NCOLS]
    const __bf16* __restrict__ zp)        // 256B zero page
{
    constexpr int WC = (NCOLS == 64) ? 2 : 1;   // col-split waves
    constexpr int WR = 4 / WC;                  // row-split waves
    constexpr int MI = BR / (WR * 16);          // 2 (CH) or 1 (COUT)
    constexpr int NI = NCOLS / (WC * 16);       // 2 (CH) or 1 (COUT)
    constexpr int ABSZ = BR * 128;              // 8K A tile (8 x 1KB chunks)
    constexpr int BSZ = NCOLS * 128;            // 8K / 2K B tile
    constexpr int BOFF = 2 * ABSZ;              // 16K
    constexpr int SNOFF = BOFF + 2 * BSZ;
    __shared__ __align__(16) char lds[SNOFF + BR * NK * 4];

    const int tid = threadIdx.x;
    const int lane = tid & 63;
    const int wid = tid >> 6;
    const int wr = wid / WC;
    const int wc = wid % WC;
    const int col = lane & 15;
    const int kgrp = lane >> 4;
    const int row0 = blockIdx.x * BR;

    // ---- preload nidx slab, permuted: snid[k*64 + (r&7)*8 + (r>>3)] = nidx[row0+r][k]
    int* snid = (int*)(lds + SNOFF);
    const int* gnid = nidx + (size_t)row0 * NK;
    for (int i = tid; i < BR * NK; i += 256) {
        int r = i / NK;
        int kk = i - r * NK;
        snid[kk * 64 + (r & 7) * 8 + (r >> 3)] = gnid[i];
    }
    __syncthreads();

    const uint32_t ldsbase = (uint32_t)(uintptr_t)(&lds[0]);
    const int qA = ((lane & 7) ^ (lane >> 3)) << 4;  // lane-constant inv-swizzle byte off

    auto issueB = [&](int k, int buf) {
        if constexpr (NCOLS == 64) {
#pragma unroll
            for (int j = 0; j < 2; ++j) {
                int jb = wid * 2 + j;
                gll16(Wt + (size_t)k * 4096 + jb * 512 + lane * 8,
                      (uint32_t)__builtin_amdgcn_readfirstlane(
                          (int)(ldsbase + BOFF + buf * BSZ + jb * 1024)));
            }
        } else {
            if (wid < 2)
                gll16(Wt + (size_t)k * 1024 + wid * 512 + lane * 8,
                      (uint32_t)__builtin_amdgcn_readfirstlane(
                          (int)(ldsbase + BOFF + buf * BSZ + wid * 1024)));
        }
    };

    // wave stages chunks c = wid*2+{0,1} (8 chunks total across 4 waves);
    // chunk c covers rows c*8 + (lane>>3); permuted snid index = (lane>>3)*8 + c
    auto issueA = [&](int k, int buf) {
        i32x2 mv = *(const i32x2*)(snid + k * 64 + (lane >> 3) * 8 + wid * 2);
#pragma unroll
        for (int j = 0; j < 2; ++j) {
            int m = mv[j];
            const __bf16* src = (m >= 0)
                ? (const __bf16*)((const char*)feat + (size_t)m * 128 + qA) : zp;
            gll16(src, (uint32_t)__builtin_amdgcn_readfirstlane(
                           (int)(ldsbase + buf * ABSZ + (wid * 2 + j) * 1024)));
        }
    };

    f32x4 acc[MI][NI];
#pragma unroll
    for (int mi = 0; mi < MI; ++mi)
#pragma unroll
        for (int ni = 0; ni < NI; ++ni)
#pragma unroll
            for (int j = 0; j < 4; ++j) acc[mi][ni][j] = 0.f;

    auto compute = [&](int k) {
        const char* Ac = lds + (k & 1) * ABSZ;
        const char* Bc = lds + BOFF + (k & 1) * BSZ;
        bf16x8 a[MI][2], b[NI][2];
#pragma unroll
        for (int mi = 0; mi < MI; ++mi) {
            int ar = wr * (MI * 16) + mi * 16 + col;
#pragma unroll
            for (int kk = 0; kk < 2; ++kk)
                a[mi][kk] = *(const bf16x8*)(Ac + ((ar * 128 + kk * 64 + kgrp * 16)
                                                   ^ ((ar & 7) << 4)));
        }
#pragma unroll
        for (int ni = 0; ni < NI; ++ni) {
            int br = wc * (NI * 16) + ni * 16 + col;
#pragma unroll
            for (int kk = 0; kk < 2; ++kk)
                b[ni][kk] = *(const bf16x8*)(Bc + ((br * 128 + kk * 64 + kgrp * 16)
                                                   ^ ((br & 7) << 4)));
        }
#pragma unroll
        for (int kk = 0; kk < 2; ++kk)
#pragma unroll
            for (int mi = 0; mi < MI; ++mi)
#pragma unroll
                for (int ni = 0; ni < NI; ++ni)
                    acc[mi][ni] = __builtin_amdgcn_mfma_f32_16x16x32_bf16(
                        a[mi][kk], b[ni][kk], acc[mi][ni], 0, 0, 0);
    };

    issueB(0, 0);
    issueA(0, 0);

    for (int k = 0; k < NK; ++k) {
        const int buf = k & 1;
        barrier_fence();                    // readers of buf^1 are done
        if (k + 1 < NK) {
            issueB(k + 1, buf ^ 1);
            issueA(k + 1, buf ^ 1);
            // retire own k-ops (2B+2A for CH); own (k+1)-ops stay in flight
            if constexpr (NCOLS == 64) { WAITVM(4); }
            else { if (wid < 2) { WAITVM(3); } else { WAITVM(2); } }
        } else {
            WAITVM(0);
        }
        barrier_fence();                    // all waves' k-tiles landed
        compute(k);
    }

    // ---- epilogue: C/D layout col=lane&15, row=(lane>>4)*4+reg ----
#pragma unroll
    for (int ni = 0; ni < NI; ++ni) {
        int c = wc * (NI * 16) + ni * 16 + col;
        float bv = bias[c];
#pragma unroll
        for (int mi = 0; mi < MI; ++mi) {
#pragma unroll
            for (int reg = 0; reg < 4; ++reg) {
                int r = row0 + wr * (MI * 16) + mi * 16 + kgrp * 4 + reg;
                float v = acc[mi][ni][reg] + bv;
                if (RELU) v = fmaxf(v, 0.f);
                if (OUT_F32) ((float*)dst)[(size_t)r * NCOLS + c] = v;
                else ((__bf16*)dst)[(size_t)r * NCOLS + c] = (__bf16)v;
            }
        }
    }
}

extern "C" void kernel_launch(void* const* d_in, const int* in_sizes, int n_in,
                              void* d_out, int out_size, void* d_ws, size_t ws_size,
                              hipStream_t stream) {
    const float* x  = (const float*)d_in[0];
    const int* nidx = (const int*)d_in[1];
    const float* W1 = (const float*)d_in[2];
    const float* b1 = (const float*)d_in[3];
    const float* W2 = (const float*)d_in[4];
    const float* b2 = (const float*)d_in[5];
    const float* W3 = (const float*)d_in[6];
    const float* b3 = (const float*)d_in[7];

    // ws: buf0(8MB: xb, later h2) | buf1(8MB: h1) | Wt1 | Wt2 | Wt3 | zeropage
    char* ws = (char*)d_ws;
    __bf16* buf0 = (__bf16*)ws;
    __bf16* buf1 = (__bf16*)(ws + 8388608);
    __bf16* Wt1  = (__bf16*)(ws + 16777216);
    __bf16* Wt2  = Wt1 + 27 * 64 * 64;
    __bf16* Wt3  = Wt2 + 27 * 64 * 64;
    __bf16* zp   = Wt3 + 27 * 16 * 64;   // 256B-aligned

    prep_kernel<<<PREP_GRID, 256, 0, stream>>>(x, W1, W2, W3, buf0, Wt1, Wt2, Wt3, (float*)zp);

    dim3 grid(N_VOX / BR);
    conv_layer<64, true,  false><<<grid, 256, 0, stream>>>(buf0, nidx, Wt1, b1, buf1, zp);
    conv_layer<64, true,  false><<<grid, 256, 0, stream>>>(buf1, nidx, Wt2, b2, buf0, zp);
    conv_layer<16, false, true ><<<grid, 256, 0, stream>>>(buf0, nidx, Wt3, b3, d_out, zp);
}